// Round 9
// baseline (6063.799 us; speedup 1.0000x reference)
//
#include <hip/hip_runtime.h>

// LSTM: B=128, T=512, I=64, H=512, O=1, fp32 in/out.
// 64 persistent WGs = 8 jg x 8 bg; 256 threads; waves fully decoupled.
// R9 hybrid exchange:
//   publish: 16B tagged-data store + flag store, BOTH fire-and-forget
//            (no producer store-ack wait; tag validation closes the race)
//   detect:  cheap 4B flag poll (R7-proven __hip_atomic relaxed AGENT)
//   acquire: one batched 32x16B sc0sc1 load + tag check; retry = rare backstop
// h words packed u32 (hi16<<16 | lo16); even-j words carry 2-bit epoch tag
// ((t+1)&3) in lo bits[1:0] (error <= 2^-15*|h|). x(t+1) loads issued before
// the store group so loop-top WAITV(3) drains exactly the x loads.

#define B_ 128
#define T_ 512
#define I_ 64
#define H_ 512

typedef __attribute__((ext_vector_type(8))) short short8;   // 8 bf16
typedef __attribute__((ext_vector_type(4))) float f32x4;
typedef __attribute__((ext_vector_type(4))) unsigned u32x4;

__device__ inline unsigned f2bf_u(float f) {
  union { float f; unsigned u; } v; v.f = f;
  return (v.u + 0x7fffu + ((v.u >> 16) & 1u)) >> 16;  // RNE
}
__device__ inline float bf2f(unsigned s) {
  union { unsigned u; float f; } v; v.u = s << 16; return v.f;
}
__device__ inline float sigm(float x) { return 1.0f / (1.0f + __expf(-x)); }
__device__ inline float tanh_(float x) { return 1.0f - 2.0f / (1.0f + __expf(2.0f * x)); }

#define WAITV(N)                                        \
  asm volatile("s_waitcnt vmcnt(" #N ")" ::: "memory"); \
  __builtin_amdgcn_sched_barrier(0)

// coherent 16B load at L3 point
#define HLOADQ(dst, base, OFF)                                            \
  asm volatile("global_load_dwordx4 %0, %1, off offset:" #OFF " sc0 sc1"  \
               : "=v"(dst) : "v"(base))

// x: read-only input, normal cached path
#define XLOADQ(dst, base, OFF)                                            \
  asm volatile("global_load_dwordx4 %0, %1, off offset:" #OFF             \
               : "=v"(dst) : "v"(base))

// coherent 16B store at L3 point (publish: data + embedded tags)
#define HSTOREQ(base, v128)                                               \
  asm volatile("global_store_dwordx4 %0, %1, off sc0 sc1"                 \
               :: "v"(base), "v"(v128) : "memory")

__global__ __launch_bounds__(256, 1) void lstm_kernel(
    const float* __restrict__ x,    // [B,T,I]
    const float* __restrict__ Wih,  // [4H,I]
    const float* __restrict__ Whh,  // [4H,H]
    const float* __restrict__ bih,  // [4H]
    const float* __restrict__ bhh,  // [4H]
    const float* __restrict__ Who,  // [1,H]
    float* __restrict__ part,       // [B][T] fp32 partials (atomicAdd)
    unsigned* __restrict__ hw,      // 2 slots x [B][H] packed u32 h words
    unsigned* __restrict__ flags)   // 8 bg x 32 per-wave flags
{
  const int bid = blockIdx.x;
  const int jg = bid >> 3;      // 0..7  hidden group (64 j)
  const int bg = bid & 7;       // 0..7  batch group (16 b)
  const int tid = threadIdx.x;
  const int w = tid >> 6;       // wave 0..3
  const int l = tid & 63;
  const int l16 = l & 15;
  const int lk = l >> 4;        // 0..3
  const int b = bg * 16 + l16;

  // ---- resident weights: bf16 A-frags, 4 M-tiles/wave ----
  short8 a_hh[4][16], a_ih[4][2];
  float bias[4][4], who[4];
#pragma unroll
  for (int m = 0; m < 4; ++m) {
    const int rowA = w * 64 + m * 16 + l16;                    // WG row = jl*4+gate
    const int grow = (rowA & 3) * 512 + jg * 64 + (rowA >> 2); // global gate row
#pragma unroll
    for (int kt = 0; kt < 16; ++kt) {
      const float* p = Whh + (size_t)grow * H_ + kt * 32 + lk * 8;
      short8 s;
#pragma unroll
      for (int e = 0; e < 8; ++e) s[e] = (short)f2bf_u(p[e]);
      a_hh[m][kt] = s;
    }
#pragma unroll
    for (int kt = 0; kt < 2; ++kt) {
      const float* p = Wih + (size_t)grow * I_ + kt * 32 + lk * 8;
      short8 s;
#pragma unroll
      for (int e = 0; e < 8; ++e) s[e] = (short)f2bf_u(p[e]);
      a_ih[m][kt] = s;
    }
    const int jm = jg * 64 + w * 16 + m * 4 + lk;
#pragma unroll
    for (int g = 0; g < 4; ++g) bias[m][g] = bih[g * 512 + jm] + bhh[g * 512 + jm];
    who[m] = Who[jm];
  }

  unsigned* const sl0 = hw;             // slot 0
  unsigned* const sl1 = hw + B_ * H_;   // slot 1
  unsigned* const fbase = flags + (size_t)bg * 32;
  unsigned* const myflag = fbase + (jg * 4 + w);
  const float* const xrow = x + (size_t)b * (T_ * I_);

  float c[4] = {0.f, 0.f, 0.f, 0.f};
  f32x4 xf0, xf1, xf2, xf3;
  {
    const float* xb = xrow + lk * 8;   // t = 0
    XLOADQ(xf0, xb, 0);   XLOADQ(xf1, xb, 16);
    XLOADQ(xf2, xb, 128); XLOADQ(xf3, xb, 144);
    WAITV(0);
  }

  u32x4 q[16][2];   // 32 x 16B validated h words

  for (int t = 0; t < T_; ++t) {
    const unsigned* hp = (t & 1) ? sl1 : sl0;   // slot holding h(t-1)
    unsigned* hn       = (t & 1) ? sl0 : sl1;   // slot for h(t)

    f32x4 acc[4][2];
#pragma unroll
    for (int m = 0; m < 4; ++m) {
      acc[m][0] = (f32x4){0.f, 0.f, 0.f, 0.f};
      acc[m][1] = (f32x4){0.f, 0.f, 0.f, 0.f};
    }

    // x(t) regs ready: drains exactly the 4 oldest vmem ops (the x loads);
    // own h-store/flag/atomic from t-1 stay in flight.
    WAITV(3);

    // ---- x projection from prefetched regs (pure VALU+MFMA) ----
#pragma unroll
    for (int kt = 0; kt < 2; ++kt) {
      f32x4 va = kt ? xf2 : xf0;
      f32x4 vb = kt ? xf3 : xf1;
      float v[8] = {va[0], va[1], va[2], va[3], vb[0], vb[1], vb[2], vb[3]};
      short8 xhi, xlo;
#pragma unroll
      for (int e = 0; e < 8; ++e) {
        unsigned hb = f2bf_u(v[e]);
        xhi[e] = (short)hb;
        xlo[e] = (short)f2bf_u(v[e] - bf2f(hb));
      }
#pragma unroll
      for (int m = 0; m < 4; ++m) {
        acc[m][0] = __builtin_amdgcn_mfma_f32_16x16x32_bf16(a_ih[m][kt], xhi, acc[m][0], 0, 0, 0);
        acc[m][1] = __builtin_amdgcn_mfma_f32_16x16x32_bf16(a_ih[m][kt], xlo, acc[m][1], 0, 0, 0);
      }
    }

    if (t > 0) {
      // ---- cheap detect: poll 32 per-wave flags (4B each) ----
      {
        const unsigned* fp = fbase + (l & 31);
        for (;;) {
          unsigned f = __hip_atomic_load(fp, __ATOMIC_RELAXED, __HIP_MEMORY_SCOPE_AGENT);
          if (__all(f >= (unsigned)t)) break;
        }
      }
      __builtin_amdgcn_fence(__ATOMIC_ACQUIRE, "workgroup");
      __builtin_amdgcn_sched_barrier(0);

      // ---- acquire: batched 32x16B load + tag validate (retry = backstop) ----
      const unsigned* ph = hp + (size_t)b * H_ + lk * 8;
      const unsigned tg = (unsigned)(t & 3);   // tag of h(t-1) data
      for (;;) {
        HLOADQ(q[0][0],  ph, 0);     HLOADQ(q[0][1],  ph, 16);
        HLOADQ(q[1][0],  ph, 128);   HLOADQ(q[1][1],  ph, 144);
        HLOADQ(q[2][0],  ph, 256);   HLOADQ(q[2][1],  ph, 272);
        HLOADQ(q[3][0],  ph, 384);   HLOADQ(q[3][1],  ph, 400);
        HLOADQ(q[4][0],  ph, 512);   HLOADQ(q[4][1],  ph, 528);
        HLOADQ(q[5][0],  ph, 640);   HLOADQ(q[5][1],  ph, 656);
        HLOADQ(q[6][0],  ph, 768);   HLOADQ(q[6][1],  ph, 784);
        HLOADQ(q[7][0],  ph, 896);   HLOADQ(q[7][1],  ph, 912);
        HLOADQ(q[8][0],  ph, 1024);  HLOADQ(q[8][1],  ph, 1040);
        HLOADQ(q[9][0],  ph, 1152);  HLOADQ(q[9][1],  ph, 1168);
        HLOADQ(q[10][0], ph, 1280);  HLOADQ(q[10][1], ph, 1296);
        HLOADQ(q[11][0], ph, 1408);  HLOADQ(q[11][1], ph, 1424);
        HLOADQ(q[12][0], ph, 1536);  HLOADQ(q[12][1], ph, 1552);
        HLOADQ(q[13][0], ph, 1664);  HLOADQ(q[13][1], ph, 1680);
        HLOADQ(q[14][0], ph, 1792);  HLOADQ(q[14][1], ph, 1808);
        HLOADQ(q[15][0], ph, 1920);  HLOADQ(q[15][1], ph, 1936);
        WAITV(0);
        unsigned bad = 0;
#pragma unroll
        for (int kt = 0; kt < 16; ++kt) {
          bad |= (q[kt][0].x ^ tg) | (q[kt][0].z ^ tg)
               | (q[kt][1].x ^ tg) | (q[kt][1].z ^ tg);
        }
        bad &= 3u;
        if (__all(bad == 0)) break;   // rare: flag overtook data
      }
      __builtin_amdgcn_sched_barrier(0);
    } else {
      WAITV(0);   // t=0: settle prologue counts (no h to read)
    }

    // ---- x(t+1) prefetch: issued BEFORE the store group ----
    {
      const int tn = (t + 1 < T_) ? t + 1 : t;
      const float* xb = xrow + tn * I_ + lk * 8;
      XLOADQ(xf0, xb, 0);   XLOADQ(xf1, xb, 16);
      XLOADQ(xf2, xb, 128); XLOADQ(xf3, xb, 144);
    }

    // ---- h recurrence: unpack (v_perm) + MFMA, all in registers ----
    if (t > 0) {
      const unsigned selh = 0x07060302u;   // hi16 of (even,odd) pair
      const unsigned sell = 0x05040100u;   // lo16 of (even,odd) pair
#pragma unroll
      for (int kt = 0; kt < 16; ++kt) {
        u32x4 qa = q[kt][0], qb = q[kt][1];
        union { unsigned u[4]; short8 s; } fh, fl;
        fh.u[0] = __builtin_amdgcn_perm(qa.y, qa.x, selh);
        fh.u[1] = __builtin_amdgcn_perm(qa.w, qa.z, selh);
        fh.u[2] = __builtin_amdgcn_perm(qb.y, qb.x, selh);
        fh.u[3] = __builtin_amdgcn_perm(qb.w, qb.z, selh);
        fl.u[0] = __builtin_amdgcn_perm(qa.y, qa.x, sell);
        fl.u[1] = __builtin_amdgcn_perm(qa.w, qa.z, sell);
        fl.u[2] = __builtin_amdgcn_perm(qb.y, qb.x, sell);
        fl.u[3] = __builtin_amdgcn_perm(qb.w, qb.z, sell);
#pragma unroll
        for (int m = 0; m < 4; ++m) {
          acc[m][0] = __builtin_amdgcn_mfma_f32_16x16x32_bf16(a_hh[m][kt], fh.s, acc[m][0], 0, 0, 0);
          acc[m][1] = __builtin_amdgcn_mfma_f32_16x16x32_bf16(a_hh[m][kt], fl.s, acc[m][1], 0, 0, 0);
        }
      }
    }

    // ---- pointwise (lane-local: 4 cells x 4 gates) + pack ----
    float p = 0.f;
    unsigned wd[4];           // packed (hi<<16 | lo) per m
#pragma unroll
    for (int m = 0; m < 4; ++m) {
      float gi = sigm(acc[m][0].x + acc[m][1].x + bias[m][0]);
      float gf = sigm(acc[m][0].y + acc[m][1].y + bias[m][1]);
      float gg = tanh_(acc[m][0].z + acc[m][1].z + bias[m][2]);
      float go = sigm(acc[m][0].w + acc[m][1].w + bias[m][3]);
      c[m] = gf * c[m] + gi * gg;
      float hv = go * tanh_(c[m]);
      p += hv * who[m];
      unsigned hb = f2bf_u(hv);
      wd[m] = (hb << 16) | f2bf_u(hv - bf2f(hb));
    }

    // ---- in-register 4x4 transpose across lk (lanes ^16, ^32) ----
    {
      unsigned r0[4], r1[4];
#pragma unroll
      for (int m = 0; m < 4; ++m) r0[m] = __shfl_xor(wd[m], 16);
#pragma unroll
      for (int m = 0; m < 4; ++m) if ((m ^ lk) & 1) wd[m] = r0[m ^ 1];
#pragma unroll
      for (int m = 0; m < 4; ++m) r1[m] = __shfl_xor(wd[m], 32);
#pragma unroll
      for (int m = 0; m < 4; ++m) if ((m ^ lk) & 2) wd[m] = r1[m ^ 2];
    }

    // ---- publish: tagged 16B data store + flag store, both in flight ----
    {
      const unsigned tgw = (unsigned)((t + 1) & 3);
      wd[0] = (wd[0] & ~3u) | tgw;
      wd[2] = (wd[2] & ~3u) | tgw;
      u32x4 sv;
      sv.x = wd[0]; sv.y = wd[1]; sv.z = wd[2]; sv.w = wd[3];
      unsigned* pst = hn + (size_t)b * H_ + jg * 64 + w * 16 + lk * 4;
      HSTOREQ(pst, sv);
    }
    if (l == 0)
      __hip_atomic_store(myflag, (unsigned)(t + 1),
                         __ATOMIC_RELAXED, __HIP_MEMORY_SCOPE_AGENT);

    // ---- projection partial (fire-and-forget) ----
    p += __shfl_xor(p, 16);
    p += __shfl_xor(p, 32);          // sum over this wave's 16 j
    if (l < 16) atomicAdd(part + (size_t)b * T_ + t, p);
  }
}

__global__ __launch_bounds__(256) void reduce_out(const float* __restrict__ part,
                                                  const float* __restrict__ b_ho,
                                                  float* __restrict__ out) {
  int i = blockIdx.x * blockDim.x + threadIdx.x;
  if (i < B_ * T_) out[i] = part[i] + b_ho[0];
}

extern "C" void kernel_launch(void* const* d_in, const int* in_sizes, int n_in,
                              void* d_out, int out_size, void* d_ws, size_t ws_size,
                              hipStream_t stream) {
  (void)in_sizes; (void)n_in; (void)out_size; (void)ws_size;
  const float* x   = (const float*)d_in[0];
  const float* Wih = (const float*)d_in[1];
  const float* Whh = (const float*)d_in[2];
  const float* bih = (const float*)d_in[3];
  const float* bhh = (const float*)d_in[4];
  const float* Who = (const float*)d_in[5];
  const float* bho = (const float*)d_in[6];
  float* out = (float*)d_out;

  // ws: hw 512KB (2 slots x [B][H] u32) | part 256KB | flags 1KB
  unsigned* hw = (unsigned*)d_ws;
  const size_t hwbytes = (size_t)2 * B_ * H_ * sizeof(unsigned);
  float* part = (float*)((char*)d_ws + hwbytes);
  const size_t pbytes = (size_t)B_ * T_ * sizeof(float);

  hipMemsetAsync(d_ws, 0, hwbytes + pbytes + 8 * 32 * sizeof(unsigned), stream);

  unsigned* flags = (unsigned*)((char*)d_ws + hwbytes + pbytes);
  lstm_kernel<<<dim3(64), dim3(256), 0, stream>>>(x, Wih, Whh, bih, bhh, Who,
                                                  part, hw, flags);
  reduce_out<<<(B_ * T_ + 255) / 256, 256, 0, stream>>>(part, bho, out);
}

// Round 10
// 2524.720 us; speedup vs baseline: 2.4018x; 2.4018x over previous
//
#include <hip/hip_runtime.h>

// LSTM: B=128, T=512, I=64, H=512, O=1, fp32 in/out.
// R10 = R7 champion + LDS staging of the h-slice (cuts coherent-fabric
// traffic 4x: each wave loads only its kt-quarter from global, stages into
// double-buffered XOR-swizzled LDS; all 4 waves read fragments from LDS).
// Exchange protocol unchanged from R7 (proven): per-wave flags via
// __hip_atomic relaxed AGENT; h data via inline-asm sc0 sc1 (L3 point);
// producer = publish stores -> WAITV(0) ack -> flag; consumer = poll 32
// flags -> load quarter -> LDS -> barrier -> MFMA from LDS.

#define B_ 128
#define T_ 512
#define I_ 64
#define H_ 512

typedef __attribute__((ext_vector_type(8))) short short8;   // 8 bf16
typedef __attribute__((ext_vector_type(4))) float f32x4;
typedef __attribute__((ext_vector_type(4))) unsigned u32x4;

__device__ inline unsigned f2bf_u(float f) {
  union { float f; unsigned u; } v; v.f = f;
  return (v.u + 0x7fffu + ((v.u >> 16) & 1u)) >> 16;  // RNE
}
__device__ inline float bf2f(unsigned s) {
  union { unsigned u; float f; } v; v.u = s << 16; return v.f;
}
__device__ inline float sigm(float x) { return 1.0f / (1.0f + __expf(-x)); }
__device__ inline float tanh_(float x) { return 1.0f - 2.0f / (1.0f + __expf(2.0f * x)); }

#define WAITV(N)                                        \
  asm volatile("s_waitcnt vmcnt(" #N ")" ::: "memory"); \
  __builtin_amdgcn_sched_barrier(0)

// coherent 16B load at L3 point
#define HLOADQ(dst, base, OFF)                                            \
  asm volatile("global_load_dwordx4 %0, %1, off offset:" #OFF " sc0 sc1"  \
               : "=v"(dst) : "v"(base))

// x: read-only input, normal cached path
#define XLOADQ(dst, base, OFF)                                            \
  asm volatile("global_load_dwordx4 %0, %1, off offset:" #OFF             \
               : "=v"(dst) : "v"(base))

// coherent 8B store at L3 point (4 lanes = contiguous 32B)
#define HSTORED2(base, v64)                                               \
  asm volatile("global_store_dwordx2 %0, %1, off sc0 sc1"                 \
               :: "v"(base), "v"(v64) : "memory")

__global__ __launch_bounds__(256, 1) void lstm_kernel(
    const float* __restrict__ x,    // [B,T,I]
    const float* __restrict__ Wih,  // [4H,I]
    const float* __restrict__ Whh,  // [4H,H]
    const float* __restrict__ bih,  // [4H]
    const float* __restrict__ bhh,  // [4H]
    const float* __restrict__ Who,  // [1,H]
    float* __restrict__ part,       // [B][T] fp32 partials (atomicAdd)
    unsigned short* __restrict__ hbuf,  // 2 bufs x (hi[B][H], lo[B][H]) bf16
    unsigned* __restrict__ flags)       // 8 bg x 32 per-wave flags
{
  const int bid = blockIdx.x;
  const int jg = bid >> 3;      // 0..7  hidden group (64 j)
  const int bg = bid & 7;       // 0..7  batch group (16 b)
  const int tid = threadIdx.x;
  const int w = tid >> 6;       // wave 0..3
  const int l = tid & 63;
  const int l16 = l & 15;
  const int lk = l >> 4;        // 0..3
  const int b = bg * 16 + l16;

  // ---- resident weights: bf16 A-frags, 4 M-tiles/wave ----
  short8 a_hh[4][16], a_ih[4][2];
  float bias[4][4], who[4];
#pragma unroll
  for (int m = 0; m < 4; ++m) {
    const int rowA = w * 64 + m * 16 + l16;                    // WG row = jl*4+gate
    const int grow = (rowA & 3) * 512 + jg * 64 + (rowA >> 2); // global gate row
#pragma unroll
    for (int kt = 0; kt < 16; ++kt) {
      const float* p = Whh + (size_t)grow * H_ + kt * 32 + lk * 8;
      short8 s;
#pragma unroll
      for (int e = 0; e < 8; ++e) s[e] = (short)f2bf_u(p[e]);
      a_hh[m][kt] = s;
    }
#pragma unroll
    for (int kt = 0; kt < 2; ++kt) {
      const float* p = Wih + (size_t)grow * I_ + kt * 32 + lk * 8;
      short8 s;
#pragma unroll
      for (int e = 0; e < 8; ++e) s[e] = (short)f2bf_u(p[e]);
      a_ih[m][kt] = s;
    }
    const int jm = jg * 64 + w * 16 + m * 4 + lk;
#pragma unroll
    for (int g = 0; g < 4; ++g) bias[m][g] = bih[g * 512 + jm] + bhh[g * 512 + jm];
    who[m] = Who[jm];
  }

  // LDS h-tile: [parity][plane][b][512 j], XOR-swizzled 16B granules.
  __shared__ unsigned short hlds[2][2][16][512];   // 64 KiB
  // ushort index within one parity: ((pl*16+bb)*512 + kt*32 + lk*8) ^ ((bb&7)<<3)
#define HOFS(pl, bb, kt) (((((pl) * 16 + (bb)) * 512) + (kt) * 32 + lk * 8) ^ (((bb) & 7) << 3))

  unsigned short* const hb0 = hbuf;
  unsigned short* const hb1 = hbuf + 2 * B_ * H_;
  unsigned* const fbase = flags + (size_t)bg * 32;
  unsigned* const myflag = fbase + (jg * 4 + w);
  const float* const xrow = x + (size_t)b * (T_ * I_);

  float c[4] = {0.f, 0.f, 0.f, 0.f};
  f32x4 xf0, xf1, xf2, xf3;
  {
    const float* xb = xrow + lk * 8;   // t = 0
    XLOADQ(xf0, xb, 0);   XLOADQ(xf1, xb, 16);
    XLOADQ(xf2, xb, 128); XLOADQ(xf3, xb, 144);
    WAITV(0);
  }

  for (int t = 0; t < T_; ++t) {
    const int pr = t & 1;
    const unsigned short* hp = pr ? hb1 : hb0;   // slot holding h(t-1)
    unsigned short* hn       = pr ? hb0 : hb1;   // slot for h(t)
    unsigned short* const hldsF = &hlds[pr][0][0][0];

    f32x4 acc[4][2];
#pragma unroll
    for (int m = 0; m < 4; ++m) {
      acc[m][0] = (f32x4){0.f, 0.f, 0.f, 0.f};
      acc[m][1] = (f32x4){0.f, 0.f, 0.f, 0.f};
    }

    // ---- x projection from prefetched regs (pure VALU+MFMA) ----
#pragma unroll
    for (int kt = 0; kt < 2; ++kt) {
      f32x4 va = kt ? xf2 : xf0;
      f32x4 vb = kt ? xf3 : xf1;
      float v[8] = {va[0], va[1], va[2], va[3], vb[0], vb[1], vb[2], vb[3]};
      short8 xhi, xlo;
#pragma unroll
      for (int e = 0; e < 8; ++e) {
        unsigned hb = f2bf_u(v[e]);
        xhi[e] = (short)hb;
        xlo[e] = (short)f2bf_u(v[e] - bf2f(hb));
      }
#pragma unroll
      for (int m = 0; m < 4; ++m) {
        acc[m][0] = __builtin_amdgcn_mfma_f32_16x16x32_bf16(a_ih[m][kt], xhi, acc[m][0], 0, 0, 0);
        acc[m][1] = __builtin_amdgcn_mfma_f32_16x16x32_bf16(a_ih[m][kt], xlo, acc[m][1], 0, 0, 0);
      }
    }

    if (t > 0) {
      // ---- cheap detect: poll 32 per-wave flags ----
      {
        const unsigned* fp = fbase + (l & 31);
        for (;;) {
          unsigned f = __hip_atomic_load(fp, __ATOMIC_RELAXED, __HIP_MEMORY_SCOPE_AGENT);
          if (__all(f >= (unsigned)t)) break;
        }
      }
      __builtin_amdgcn_fence(__ATOMIC_ACQUIRE, "workgroup");
      __builtin_amdgcn_sched_barrier(0);

      // ---- this wave's kt-quarter: 8x16B global loads + x(t+1) issue ----
      u32x4 qh[4], ql[4];
      {
        const unsigned short* phh = hp + (size_t)b * H_ + w * 128 + lk * 8;
        const unsigned short* pll = phh + (size_t)(B_ * H_);
        HLOADQ(qh[0], phh, 0);   HLOADQ(qh[1], phh, 64);
        HLOADQ(qh[2], phh, 128); HLOADQ(qh[3], phh, 192);
        HLOADQ(ql[0], pll, 0);   HLOADQ(ql[1], pll, 64);
        HLOADQ(ql[2], pll, 128); HLOADQ(ql[3], pll, 192);
        const int tn = (t + 1 < T_) ? t + 1 : t;
        const float* xb = xrow + tn * I_ + lk * 8;
        XLOADQ(xf0, xb, 0);   XLOADQ(xf1, xb, 16);
        XLOADQ(xf2, xb, 128); XLOADQ(xf3, xb, 144);
      }
      WAITV(4);   // 8 h-quarter loads done; 4 x loads still in flight

      // ---- stage into swizzled LDS ----
#pragma unroll
      for (int i = 0; i < 4; ++i) {
        *(u32x4*)&hldsF[HOFS(0, l16, 4 * w + i)] = qh[i];
        *(u32x4*)&hldsF[HOFS(1, l16, 4 * w + i)] = ql[i];
      }
      __syncthreads();

      // ---- h recurrence: fragments from LDS (compiler pipelines lgkmcnt) ----
#pragma unroll
      for (int kt = 0; kt < 16; ++kt) {
        short8 fh = *(const short8*)&hldsF[HOFS(0, l16, kt)];
        short8 fl = *(const short8*)&hldsF[HOFS(1, l16, kt)];
#pragma unroll
        for (int m = 0; m < 4; ++m) {
          acc[m][0] = __builtin_amdgcn_mfma_f32_16x16x32_bf16(a_hh[m][kt], fh, acc[m][0], 0, 0, 0);
          acc[m][1] = __builtin_amdgcn_mfma_f32_16x16x32_bf16(a_hh[m][kt], fl, acc[m][1], 0, 0, 0);
        }
      }
    } else {
      // t=0: no h term; just issue x(1) prefetch
      const float* xb = xrow + I_ + lk * 8;
      XLOADQ(xf0, xb, 0);   XLOADQ(xf1, xb, 16);
      XLOADQ(xf2, xb, 128); XLOADQ(xf3, xb, 144);
    }

    // ---- pointwise (lane-local: 4 cells x 4 gates) + pack ----
    float p = 0.f;
    unsigned wd[4];           // packed (hi | lo<<16) per m
#pragma unroll
    for (int m = 0; m < 4; ++m) {
      float gi = sigm(acc[m][0].x + acc[m][1].x + bias[m][0]);
      float gf = sigm(acc[m][0].y + acc[m][1].y + bias[m][1]);
      float gg = tanh_(acc[m][0].z + acc[m][1].z + bias[m][2]);
      float go = sigm(acc[m][0].w + acc[m][1].w + bias[m][3]);
      c[m] = gf * c[m] + gi * gg;
      float hv = go * tanh_(c[m]);
      p += hv * who[m];
      unsigned hb = f2bf_u(hv);
      wd[m] = hb | (f2bf_u(hv - bf2f(hb)) << 16);
    }

    // ---- in-register 4x4 transpose across lk (lanes ^16, ^32) ----
    {
      unsigned r0[4], r1[4];
#pragma unroll
      for (int m = 0; m < 4; ++m) r0[m] = __shfl_xor(wd[m], 16);
#pragma unroll
      for (int m = 0; m < 4; ++m) if ((m ^ lk) & 1) wd[m] = r0[m ^ 1];
#pragma unroll
      for (int m = 0; m < 4; ++m) r1[m] = __shfl_xor(wd[m], 32);
#pragma unroll
      for (int m = 0; m < 4; ++m) if ((m ^ lk) & 2) wd[m] = r1[m ^ 2];
    }

    // ---- publish: coalesced 8B stores per plane (R7-proven) ----
    {
      unsigned hi01 = (wd[0] & 0xffffu) | (wd[1] << 16);
      unsigned hi23 = (wd[2] & 0xffffu) | (wd[3] << 16);
      unsigned lo01 = (wd[0] >> 16) | (wd[1] & 0xffff0000u);
      unsigned lo23 = (wd[2] >> 16) | (wd[3] & 0xffff0000u);
      unsigned long long hiq = (unsigned long long)hi01 | ((unsigned long long)hi23 << 32);
      unsigned long long loq = (unsigned long long)lo01 | ((unsigned long long)lo23 << 32);
      unsigned short* ph = hn + (size_t)b * H_ + jg * 64 + w * 16 + lk * 4;
      HSTORED2(ph, hiq);
      HSTORED2(ph + B_ * H_, loq);
    }

    WAITV(0);  // h stores acked at L3; x(t+1) regs ready
    if (l == 0)
      __hip_atomic_store(myflag, (unsigned)(t + 1),
                         __ATOMIC_RELAXED, __HIP_MEMORY_SCOPE_AGENT);

    // ---- projection partial (fire-and-forget, after flag) ----
    p += __shfl_xor(p, 16);
    p += __shfl_xor(p, 32);          // sum over this wave's 16 j
    if (l < 16) atomicAdd(part + (size_t)b * T_ + t, p);
  }
#undef HOFS
}

__global__ __launch_bounds__(256) void reduce_out(const float* __restrict__ part,
                                                  const float* __restrict__ b_ho,
                                                  float* __restrict__ out) {
  int i = blockIdx.x * blockDim.x + threadIdx.x;
  if (i < B_ * T_) out[i] = part[i] + b_ho[0];
}

extern "C" void kernel_launch(void* const* d_in, const int* in_sizes, int n_in,
                              void* d_out, int out_size, void* d_ws, size_t ws_size,
                              hipStream_t stream) {
  (void)in_sizes; (void)n_in; (void)out_size; (void)ws_size;
  const float* x   = (const float*)d_in[0];
  const float* Wih = (const float*)d_in[1];
  const float* Whh = (const float*)d_in[2];
  const float* bih = (const float*)d_in[3];
  const float* bhh = (const float*)d_in[4];
  const float* Who = (const float*)d_in[5];
  const float* bho = (const float*)d_in[6];
  float* out = (float*)d_out;

  // ws: hbuf 512KB | part 256KB | flags 1KB
  unsigned short* hbuf = (unsigned short*)d_ws;
  const size_t hbytes = (size_t)2 * 2 * B_ * H_ * sizeof(unsigned short);
  float* part = (float*)((char*)d_ws + hbytes);
  const size_t pbytes = (size_t)B_ * T_ * sizeof(float);
  unsigned* flags = (unsigned*)((char*)d_ws + hbytes + pbytes);

  // zero partials + flags (h slots are written before ever being read)
  hipMemsetAsync((char*)d_ws + hbytes, 0, pbytes + 8 * 32 * sizeof(unsigned), stream);

  lstm_kernel<<<dim3(64), dim3(256), 0, stream>>>(x, Wih, Whh, bih, bhh, Who,
                                                  part, hbuf, flags);
  reduce_out<<<(B_ * T_ + 255) / 256, 256, 0, stream>>>(part, bho, out);
}

// Round 11
// 2521.038 us; speedup vs baseline: 2.4053x; 1.0015x over previous
//
#include <hip/hip_runtime.h>

// LSTM: B=128, T=512, I=64, H=512, O=1, fp32 in/out.
// R10 = R7 champion + LDS staging of the h-slice (cuts coherent-fabric
// traffic 4x: each wave loads only its kt-quarter from global, stages into
// double-buffered XOR-swizzled LDS; all 4 waves read fragments from LDS).
// Exchange protocol unchanged from R7 (proven): per-wave flags via
// __hip_atomic relaxed AGENT; h data via inline-asm sc0 sc1 (L3 point);
// producer = publish stores -> WAITV(0) ack -> flag; consumer = poll 32
// flags -> load quarter -> LDS -> barrier -> MFMA from LDS.

#define B_ 128
#define T_ 512
#define I_ 64
#define H_ 512

typedef __attribute__((ext_vector_type(8))) short short8;   // 8 bf16
typedef __attribute__((ext_vector_type(4))) float f32x4;
typedef __attribute__((ext_vector_type(4))) unsigned u32x4;

__device__ inline unsigned f2bf_u(float f) {
  union { float f; unsigned u; } v; v.f = f;
  return (v.u + 0x7fffu + ((v.u >> 16) & 1u)) >> 16;  // RNE
}
__device__ inline float bf2f(unsigned s) {
  union { unsigned u; float f; } v; v.u = s << 16; return v.f;
}
__device__ inline float sigm(float x) { return 1.0f / (1.0f + __expf(-x)); }
__device__ inline float tanh_(float x) { return 1.0f - 2.0f / (1.0f + __expf(2.0f * x)); }

#define WAITV(N)                                        \
  asm volatile("s_waitcnt vmcnt(" #N ")" ::: "memory"); \
  __builtin_amdgcn_sched_barrier(0)

// coherent 16B load at L3 point
#define HLOADQ(dst, base, OFF)                                            \
  asm volatile("global_load_dwordx4 %0, %1, off offset:" #OFF " sc0 sc1"  \
               : "=v"(dst) : "v"(base))

// x: read-only input, normal cached path
#define XLOADQ(dst, base, OFF)                                            \
  asm volatile("global_load_dwordx4 %0, %1, off offset:" #OFF             \
               : "=v"(dst) : "v"(base))

// coherent 8B store at L3 point (4 lanes = contiguous 32B)
#define HSTORED2(base, v64)                                               \
  asm volatile("global_store_dwordx2 %0, %1, off sc0 sc1"                 \
               :: "v"(base), "v"(v64) : "memory")

__global__ __launch_bounds__(256, 1) void lstm_kernel(
    const float* __restrict__ x,    // [B,T,I]
    const float* __restrict__ Wih,  // [4H,I]
    const float* __restrict__ Whh,  // [4H,H]
    const float* __restrict__ bih,  // [4H]
    const float* __restrict__ bhh,  // [4H]
    const float* __restrict__ Who,  // [1,H]
    float* __restrict__ part,       // [B][T] fp32 partials (atomicAdd)
    unsigned short* __restrict__ hbuf,  // 2 bufs x (hi[B][H], lo[B][H]) bf16
    unsigned* __restrict__ flags)       // 8 bg x 32 per-wave flags
{
  const int bid = blockIdx.x;
  const int jg = bid >> 3;      // 0..7  hidden group (64 j)
  const int bg = bid & 7;       // 0..7  batch group (16 b)
  const int tid = threadIdx.x;
  const int w = tid >> 6;       // wave 0..3
  const int l = tid & 63;
  const int l16 = l & 15;
  const int lk = l >> 4;        // 0..3
  const int b = bg * 16 + l16;

  // ---- resident weights: bf16 A-frags, 4 M-tiles/wave ----
  short8 a_hh[4][16], a_ih[4][2];
  float bias[4][4], who[4];
#pragma unroll
  for (int m = 0; m < 4; ++m) {
    const int rowA = w * 64 + m * 16 + l16;                    // WG row = jl*4+gate
    const int grow = (rowA & 3) * 512 + jg * 64 + (rowA >> 2); // global gate row
#pragma unroll
    for (int kt = 0; kt < 16; ++kt) {
      const float* p = Whh + (size_t)grow * H_ + kt * 32 + lk * 8;
      short8 s;
#pragma unroll
      for (int e = 0; e < 8; ++e) s[e] = (short)f2bf_u(p[e]);
      a_hh[m][kt] = s;
    }
#pragma unroll
    for (int kt = 0; kt < 2; ++kt) {
      const float* p = Wih + (size_t)grow * I_ + kt * 32 + lk * 8;
      short8 s;
#pragma unroll
      for (int e = 0; e < 8; ++e) s[e] = (short)f2bf_u(p[e]);
      a_ih[m][kt] = s;
    }
    const int jm = jg * 64 + w * 16 + m * 4 + lk;
#pragma unroll
    for (int g = 0; g < 4; ++g) bias[m][g] = bih[g * 512 + jm] + bhh[g * 512 + jm];
    who[m] = Who[jm];
  }

  // LDS h-tile: [parity][plane][b][512 j], XOR-swizzled 16B granules.
  __shared__ unsigned short hlds[2][2][16][512];   // 64 KiB
  // ushort index within one parity: ((pl*16+bb)*512 + kt*32 + lk*8) ^ ((bb&7)<<3)
#define HOFS(pl, bb, kt) (((((pl) * 16 + (bb)) * 512) + (kt) * 32 + lk * 8) ^ (((bb) & 7) << 3))

  unsigned short* const hb0 = hbuf;
  unsigned short* const hb1 = hbuf + 2 * B_ * H_;
  unsigned* const fbase = flags + (size_t)bg * 32;
  unsigned* const myflag = fbase + (jg * 4 + w);
  const float* const xrow = x + (size_t)b * (T_ * I_);

  float c[4] = {0.f, 0.f, 0.f, 0.f};
  f32x4 xf0, xf1, xf2, xf3;
  {
    const float* xb = xrow + lk * 8;   // t = 0
    XLOADQ(xf0, xb, 0);   XLOADQ(xf1, xb, 16);
    XLOADQ(xf2, xb, 128); XLOADQ(xf3, xb, 144);
    WAITV(0);
  }

  for (int t = 0; t < T_; ++t) {
    const int pr = t & 1;
    const unsigned short* hp = pr ? hb1 : hb0;   // slot holding h(t-1)
    unsigned short* hn       = pr ? hb0 : hb1;   // slot for h(t)
    unsigned short* const hldsF = &hlds[pr][0][0][0];

    f32x4 acc[4][2];
#pragma unroll
    for (int m = 0; m < 4; ++m) {
      acc[m][0] = (f32x4){0.f, 0.f, 0.f, 0.f};
      acc[m][1] = (f32x4){0.f, 0.f, 0.f, 0.f};
    }

    // ---- x projection from prefetched regs (pure VALU+MFMA) ----
#pragma unroll
    for (int kt = 0; kt < 2; ++kt) {
      f32x4 va = kt ? xf2 : xf0;
      f32x4 vb = kt ? xf3 : xf1;
      float v[8] = {va[0], va[1], va[2], va[3], vb[0], vb[1], vb[2], vb[3]};
      short8 xhi, xlo;
#pragma unroll
      for (int e = 0; e < 8; ++e) {
        unsigned hb = f2bf_u(v[e]);
        xhi[e] = (short)hb;
        xlo[e] = (short)f2bf_u(v[e] - bf2f(hb));
      }
#pragma unroll
      for (int m = 0; m < 4; ++m) {
        acc[m][0] = __builtin_amdgcn_mfma_f32_16x16x32_bf16(a_ih[m][kt], xhi, acc[m][0], 0, 0, 0);
        acc[m][1] = __builtin_amdgcn_mfma_f32_16x16x32_bf16(a_ih[m][kt], xlo, acc[m][1], 0, 0, 0);
      }
    }

    if (t > 0) {
      // ---- cheap detect: poll 32 per-wave flags ----
      {
        const unsigned* fp = fbase + (l & 31);
        for (;;) {
          unsigned f = __hip_atomic_load(fp, __ATOMIC_RELAXED, __HIP_MEMORY_SCOPE_AGENT);
          if (__all(f >= (unsigned)t)) break;
        }
      }
      __builtin_amdgcn_fence(__ATOMIC_ACQUIRE, "workgroup");
      __builtin_amdgcn_sched_barrier(0);

      // ---- this wave's kt-quarter: 8x16B global loads + x(t+1) issue ----
      u32x4 qh[4], ql[4];
      {
        const unsigned short* phh = hp + (size_t)b * H_ + w * 128 + lk * 8;
        const unsigned short* pll = phh + (size_t)(B_ * H_);
        HLOADQ(qh[0], phh, 0);   HLOADQ(qh[1], phh, 64);
        HLOADQ(qh[2], phh, 128); HLOADQ(qh[3], phh, 192);
        HLOADQ(ql[0], pll, 0);   HLOADQ(ql[1], pll, 64);
        HLOADQ(ql[2], pll, 128); HLOADQ(ql[3], pll, 192);
        const int tn = (t + 1 < T_) ? t + 1 : t;
        const float* xb = xrow + tn * I_ + lk * 8;
        XLOADQ(xf0, xb, 0);   XLOADQ(xf1, xb, 16);
        XLOADQ(xf2, xb, 128); XLOADQ(xf3, xb, 144);
      }
      WAITV(4);   // 8 h-quarter loads done; 4 x loads still in flight

      // ---- stage into swizzled LDS ----
#pragma unroll
      for (int i = 0; i < 4; ++i) {
        *(u32x4*)&hldsF[HOFS(0, l16, 4 * w + i)] = qh[i];
        *(u32x4*)&hldsF[HOFS(1, l16, 4 * w + i)] = ql[i];
      }
      __syncthreads();

      // ---- h recurrence: fragments from LDS (compiler pipelines lgkmcnt) ----
#pragma unroll
      for (int kt = 0; kt < 16; ++kt) {
        short8 fh = *(const short8*)&hldsF[HOFS(0, l16, kt)];
        short8 fl = *(const short8*)&hldsF[HOFS(1, l16, kt)];
#pragma unroll
        for (int m = 0; m < 4; ++m) {
          acc[m][0] = __builtin_amdgcn_mfma_f32_16x16x32_bf16(a_hh[m][kt], fh, acc[m][0], 0, 0, 0);
          acc[m][1] = __builtin_amdgcn_mfma_f32_16x16x32_bf16(a_hh[m][kt], fl, acc[m][1], 0, 0, 0);
        }
      }
    } else {
      // t=0: no h term; just issue x(1) prefetch
      const float* xb = xrow + I_ + lk * 8;
      XLOADQ(xf0, xb, 0);   XLOADQ(xf1, xb, 16);
      XLOADQ(xf2, xb, 128); XLOADQ(xf3, xb, 144);
    }

    // ---- pointwise (lane-local: 4 cells x 4 gates) + pack ----
    float p = 0.f;
    unsigned wd[4];           // packed (hi | lo<<16) per m
#pragma unroll
    for (int m = 0; m < 4; ++m) {
      float gi = sigm(acc[m][0].x + acc[m][1].x + bias[m][0]);
      float gf = sigm(acc[m][0].y + acc[m][1].y + bias[m][1]);
      float gg = tanh_(acc[m][0].z + acc[m][1].z + bias[m][2]);
      float go = sigm(acc[m][0].w + acc[m][1].w + bias[m][3]);
      c[m] = gf * c[m] + gi * gg;
      float hv = go * tanh_(c[m]);
      p += hv * who[m];
      unsigned hb = f2bf_u(hv);
      wd[m] = hb | (f2bf_u(hv - bf2f(hb)) << 16);
    }

    // ---- in-register 4x4 transpose across lk (lanes ^16, ^32) ----
    {
      unsigned r0[4], r1[4];
#pragma unroll
      for (int m = 0; m < 4; ++m) r0[m] = __shfl_xor(wd[m], 16);
#pragma unroll
      for (int m = 0; m < 4; ++m) if ((m ^ lk) & 1) wd[m] = r0[m ^ 1];
#pragma unroll
      for (int m = 0; m < 4; ++m) r1[m] = __shfl_xor(wd[m], 32);
#pragma unroll
      for (int m = 0; m < 4; ++m) if ((m ^ lk) & 2) wd[m] = r1[m ^ 2];
    }

    // ---- publish: coalesced 8B stores per plane (R7-proven) ----
    {
      unsigned hi01 = (wd[0] & 0xffffu) | (wd[1] << 16);
      unsigned hi23 = (wd[2] & 0xffffu) | (wd[3] << 16);
      unsigned lo01 = (wd[0] >> 16) | (wd[1] & 0xffff0000u);
      unsigned lo23 = (wd[2] >> 16) | (wd[3] & 0xffff0000u);
      unsigned long long hiq = (unsigned long long)hi01 | ((unsigned long long)hi23 << 32);
      unsigned long long loq = (unsigned long long)lo01 | ((unsigned long long)lo23 << 32);
      unsigned short* ph = hn + (size_t)b * H_ + jg * 64 + w * 16 + lk * 4;
      HSTORED2(ph, hiq);
      HSTORED2(ph + B_ * H_, loq);
    }

    WAITV(0);  // h stores acked at L3; x(t+1) regs ready
    if (l == 0)
      __hip_atomic_store(myflag, (unsigned)(t + 1),
                         __ATOMIC_RELAXED, __HIP_MEMORY_SCOPE_AGENT);

    // ---- projection partial (fire-and-forget, after flag) ----
    p += __shfl_xor(p, 16);
    p += __shfl_xor(p, 32);          // sum over this wave's 16 j
    if (l < 16) atomicAdd(part + (size_t)b * T_ + t, p);
  }
#undef HOFS
}

__global__ __launch_bounds__(256) void reduce_out(const float* __restrict__ part,
                                                  const float* __restrict__ b_ho,
                                                  float* __restrict__ out) {
  int i = blockIdx.x * blockDim.x + threadIdx.x;
  if (i < B_ * T_) out[i] = part[i] + b_ho[0];
}

extern "C" void kernel_launch(void* const* d_in, const int* in_sizes, int n_in,
                              void* d_out, int out_size, void* d_ws, size_t ws_size,
                              hipStream_t stream) {
  (void)in_sizes; (void)n_in; (void)out_size; (void)ws_size;
  const float* x   = (const float*)d_in[0];
  const float* Wih = (const float*)d_in[1];
  const float* Whh = (const float*)d_in[2];
  const float* bih = (const float*)d_in[3];
  const float* bhh = (const float*)d_in[4];
  const float* Who = (const float*)d_in[5];
  const float* bho = (const float*)d_in[6];
  float* out = (float*)d_out;

  // ws: hbuf 512KB | part 256KB | flags 1KB
  unsigned short* hbuf = (unsigned short*)d_ws;
  const size_t hbytes = (size_t)2 * 2 * B_ * H_ * sizeof(unsigned short);
  float* part = (float*)((char*)d_ws + hbytes);
  const size_t pbytes = (size_t)B_ * T_ * sizeof(float);
  unsigned* flags = (unsigned*)((char*)d_ws + hbytes + pbytes);

  // zero partials + flags (h slots are written before ever being read)
  hipMemsetAsync((char*)d_ws + hbytes, 0, pbytes + 8 * 32 * sizeof(unsigned), stream);

  lstm_kernel<<<dim3(64), dim3(256), 0, stream>>>(x, Wih, Whh, bih, bhh, Who,
                                                  part, hbuf, flags);
  reduce_out<<<(B_ * T_ + 255) / 256, 256, 0, stream>>>(part, bho, out);
}